// Round 1
// baseline (1532.208 us; speedup 1.0000x reference)
//
#include <hip/hip_runtime.h>

// Problem constants
constexpr int kBS = 8;
constexpr int kC  = 128;   // channels
constexpr int kCH = 64;    // proj channels (C/2)
constexpr int kN  = 4096;  // H*W tokens

// Flash tiling
constexpr int kR  = 32;    // Q rows per block
constexpr int kTK = 64;    // key tile

// ---------------------------------------------------------------------------
// Kernel P: 1x1-conv projection  out[b][d][n] = act(bias[d] + sum_c W[d][c]*X[b][c][n])
// Block: 32 tokens x 32 out-channels (thread: 1 token x 4 channels).
// W rows staged in LDS with +1 padding (stride 129) -> conflict-free broadcast reads.
// ---------------------------------------------------------------------------
__global__ __launch_bounds__(256) void proj_kernel(
    const float* __restrict__ X,      // [8][kC][kN]
    const float* __restrict__ W,      // [OC][kC]
    const float* __restrict__ bias,   // [OC]
    float* __restrict__ out,          // [8][OC][kN]
    int OC, int do_relu)
{
    __shared__ float ws[32 * 129];
    const int t = threadIdx.x;
    const int mt = blockIdx.x;        // kN/32 = 128 token tiles
    const int d0 = blockIdx.y * 32;   // channel tile
    const int b = blockIdx.z;

    for (int idx = t; idx < 32 * kC; idx += 256) {
        int dd = idx >> 7, c = idx & 127;
        ws[dd * 129 + c] = W[(size_t)(d0 + dd) * kC + c];
    }
    __syncthreads();

    const int m = mt * 32 + (t & 31);
    const int dl = t >> 5;            // 0..7 ; covers d = dl + 8k
    const float* xp = X + ((size_t)b * kC) * kN + m;

    float acc[4];
    #pragma unroll
    for (int k = 0; k < 4; ++k) acc[k] = bias[d0 + dl + 8 * k];

    #pragma unroll 4
    for (int c = 0; c < kC; ++c) {
        float x = xp[(size_t)c * kN];
        #pragma unroll
        for (int k = 0; k < 4; ++k)
            acc[k] = fmaf(x, ws[(dl + 8 * k) * 129 + c], acc[k]);
    }
    #pragma unroll
    for (int k = 0; k < 4; ++k) {
        float v = do_relu ? fmaxf(acc[k], 0.0f) : acc[k];
        out[((size_t)b * OC + d0 + dl + 8 * k) * kN + m] = v;
    }
}

// ---------------------------------------------------------------------------
// Kernel T: Vt[b][n][c] = ref[b][c][n]   (32x32 LDS tile transpose, both sides coalesced)
// ---------------------------------------------------------------------------
__global__ __launch_bounds__(256) void transpose_kernel(
    const float* __restrict__ ref, float* __restrict__ Vt)
{
    __shared__ float tile[32][33];
    const int blk = blockIdx.x;
    const int ct = blk & 3;            // 4 c-tiles
    const int mt = (blk >> 2) & 127;   // 128 m-tiles
    const int b  = blk >> 9;
    const int c0 = ct * 32, m0 = mt * 32;

    {
        const int mi = threadIdx.x & 31;
        const int cq = threadIdx.x >> 5;    // 0..7
        #pragma unroll
        for (int k = 0; k < 4; ++k) {
            int ci = cq + k * 8;
            tile[mi][ci] = ref[((size_t)b * kC + c0 + ci) * kN + m0 + mi];
        }
    }
    __syncthreads();
    {
        const int ci = threadIdx.x & 31;
        const int mq = threadIdx.x >> 5;
        #pragma unroll
        for (int k = 0; k < 4; ++k) {
            int mi = mq + k * 8;
            Vt[((size_t)b * kN + m0 + mi) * kC + c0 + ci] = tile[mi][ci];
        }
    }
}

// ---------------------------------------------------------------------------
// Kernel F: flash attention + gate epilogue.
// Grid: 1024 blocks = 8 batches x 128 row-tiles (batch = blockIdx&7 -> XCD L2 locality).
// Thread (rg = t>>5, cg = t&31): owns rows r0..r0+3, O columns 4cg..4cg+3,
// and score columns m in {cg, cg+32} of each key tile.
// Online softmax fully in registers via 32-lane shuffle reductions (rows are
// partitioned per half-wave, so no LDS/barrier needed between score and PV).
// ---------------------------------------------------------------------------
__global__ __launch_bounds__(256) void flash_kernel(
    const float* __restrict__ ref,   // [8][kC][kN] (V fallback path)
    const float* __restrict__ Qw,    // [8][kCH][kN]
    const float* __restrict__ Kw,    // [8][kCH][kN]
    const float* __restrict__ Gw,    // [8][kC][kN]  gate (att_out)
    const float* __restrict__ Vt,    // [8][kN][kC]  or unused
    float* __restrict__ out,         // [8][kC][kN]
    int use_vt)
{
    __shared__ float Qs[kCH * 33];        // Qs[d][r], stride 33 (broadcast reads)
    __shared__ float Kt[kCH * kTK];       // Kt[d][m], stride 64 (lane-varying cg reads)
    __shared__ float Vs[kTK * kC];        // Vs[m][c], stride 128 (float4 reads)

    const int t  = threadIdx.x;
    const int b  = blockIdx.x & 7;
    const int n0 = (blockIdx.x >> 3) << 5;   // * kR
    const int rg = t >> 5, cg = t & 31;
    const int r0 = rg << 2;
    const int hb = t & 32;                   // half-wave base lane
    const int c4 = cg << 2;

    const float* Qb   = Qw + ((size_t)b * kCH) * kN;
    const float* Kb   = Kw + ((size_t)b * kCH) * kN;
    const float* refb = ref + ((size_t)b * kC) * kN;
    const float* Vtb  = Vt + ((size_t)b * kN) * kC;

    // ---- load Q tile: Qs[d][r] <- Qw[b][d][n0+r] ----
    #pragma unroll
    for (int k = 0; k < 2; ++k) {
        int g = t + k * 256;                 // 0..511 float4 groups (64 d x 8 ngroups)
        int d = g >> 3, ng = (g & 7) << 2;
        float4 v = *(const float4*)(Qb + (size_t)d * kN + n0 + ng);
        Qs[d * 33 + ng + 0] = v.x;
        Qs[d * 33 + ng + 1] = v.y;
        Qs[d * 33 + ng + 2] = v.z;
        Qs[d * 33 + ng + 3] = v.w;
    }

    float O[4][4];
    #pragma unroll
    for (int i = 0; i < 4; ++i)
        #pragma unroll
        for (int j = 0; j < 4; ++j) O[i][j] = 0.0f;
    float m_run[4], l_run[4];
    #pragma unroll
    for (int i = 0; i < 4; ++i) { m_run[i] = -3.0e38f; l_run[i] = 0.0f; }

    for (int kt = 0; kt < kN / kTK; ++kt) {
        const int m0 = kt * kTK;
        __syncthreads();   // previous tile fully consumed (and Qs visible at kt=0)

        // ---- load K tile: Kt[d][m] <- Kw[b][d][m0+m] (coalesced, b128 LDS writes) ----
        #pragma unroll
        for (int k = 0; k < 4; ++k) {
            int g = t + k * 256;             // 0..1023 (64 d x 16 mgroups)
            int d = g >> 4, mg = (g & 15) << 2;
            float4 v = *(const float4*)(Kb + (size_t)d * kN + m0 + mg);
            *(float4*)(Kt + d * kTK + mg) = v;
        }
        // ---- load V tile: Vs[m][c] ----
        if (use_vt) {
            const float* src = Vtb + (size_t)m0 * kC;
            #pragma unroll
            for (int k = 0; k < 8; ++k) {
                int fl = (t + k * 256) << 2;
                *(float4*)(Vs + fl) = *(const float4*)(src + fl);
            }
        } else {
            int c = t & 127, half = t >> 7;
            const float* src = refb + (size_t)c * kN + m0 + half * 32;
            #pragma unroll
            for (int k = 0; k < 8; ++k) {
                float4 v = *(const float4*)(src + 4 * k);
                int mm = half * 32 + 4 * k;
                Vs[(mm + 0) * kC + c] = v.x;
                Vs[(mm + 1) * kC + c] = v.y;
                Vs[(mm + 2) * kC + c] = v.z;
                Vs[(mm + 3) * kC + c] = v.w;
            }
        }
        __syncthreads();

        // ---- QK^T: s0 -> key m0+cg, s1 -> key m0+cg+32, rows r0..r0+3 ----
        float s0[4] = {0.f, 0.f, 0.f, 0.f};
        float s1[4] = {0.f, 0.f, 0.f, 0.f};
        #pragma unroll 8
        for (int d = 0; d < kCH; ++d) {
            float k0 = Kt[d * kTK + cg];
            float k1 = Kt[d * kTK + cg + 32];
            float q0 = Qs[d * 33 + r0 + 0];
            float q1 = Qs[d * 33 + r0 + 1];
            float q2 = Qs[d * 33 + r0 + 2];
            float q3 = Qs[d * 33 + r0 + 3];
            s0[0] = fmaf(q0, k0, s0[0]); s1[0] = fmaf(q0, k1, s1[0]);
            s0[1] = fmaf(q1, k0, s0[1]); s1[1] = fmaf(q1, k1, s1[1]);
            s0[2] = fmaf(q2, k0, s0[2]); s1[2] = fmaf(q2, k1, s1[2]);
            s0[3] = fmaf(q3, k0, s0[3]); s1[3] = fmaf(q3, k1, s1[3]);
        }

        // ---- online softmax (per row, across the 32 lanes of this half-wave) ----
        float p0[4], p1[4];
        #pragma unroll
        for (int i = 0; i < 4; ++i) {
            float tm = fmaxf(s0[i], s1[i]);
            tm = fmaxf(tm, __shfl_xor(tm, 1, 64));
            tm = fmaxf(tm, __shfl_xor(tm, 2, 64));
            tm = fmaxf(tm, __shfl_xor(tm, 4, 64));
            tm = fmaxf(tm, __shfl_xor(tm, 8, 64));
            tm = fmaxf(tm, __shfl_xor(tm, 16, 64));
            float mn = fmaxf(m_run[i], tm);
            float alpha = __expf(m_run[i] - mn);
            m_run[i] = mn;
            p0[i] = __expf(s0[i] - mn);
            p1[i] = __expf(s1[i] - mn);
            float ps = p0[i] + p1[i];
            ps += __shfl_xor(ps, 1, 64);
            ps += __shfl_xor(ps, 2, 64);
            ps += __shfl_xor(ps, 4, 64);
            ps += __shfl_xor(ps, 8, 64);
            ps += __shfl_xor(ps, 16, 64);
            l_run[i] = l_run[i] * alpha + ps;
            O[i][0] *= alpha; O[i][1] *= alpha; O[i][2] *= alpha; O[i][3] *= alpha;
        }

        // ---- PV: O[i][j] += P[r0+i][m] * V[m][c4+j]; P broadcast via shuffle ----
        #pragma unroll 2
        for (int m = 0; m < 32; ++m) {
            float4 v = *(const float4*)(Vs + m * kC + c4);
            float pa = __shfl(p0[0], hb | m, 64);
            float pb = __shfl(p0[1], hb | m, 64);
            float pc = __shfl(p0[2], hb | m, 64);
            float pd = __shfl(p0[3], hb | m, 64);
            O[0][0] = fmaf(pa, v.x, O[0][0]); O[0][1] = fmaf(pa, v.y, O[0][1]);
            O[0][2] = fmaf(pa, v.z, O[0][2]); O[0][3] = fmaf(pa, v.w, O[0][3]);
            O[1][0] = fmaf(pb, v.x, O[1][0]); O[1][1] = fmaf(pb, v.y, O[1][1]);
            O[1][2] = fmaf(pb, v.z, O[1][2]); O[1][3] = fmaf(pb, v.w, O[1][3]);
            O[2][0] = fmaf(pc, v.x, O[2][0]); O[2][1] = fmaf(pc, v.y, O[2][1]);
            O[2][2] = fmaf(pc, v.z, O[2][2]); O[2][3] = fmaf(pc, v.w, O[2][3]);
            O[3][0] = fmaf(pd, v.x, O[3][0]); O[3][1] = fmaf(pd, v.y, O[3][1]);
            O[3][2] = fmaf(pd, v.z, O[3][2]); O[3][3] = fmaf(pd, v.w, O[3][3]);
        }
        #pragma unroll 2
        for (int m = 32; m < 64; ++m) {
            float4 v = *(const float4*)(Vs + m * kC + c4);
            int sl = hb | (m - 32);
            float pa = __shfl(p1[0], sl, 64);
            float pb = __shfl(p1[1], sl, 64);
            float pc = __shfl(p1[2], sl, 64);
            float pd = __shfl(p1[3], sl, 64);
            O[0][0] = fmaf(pa, v.x, O[0][0]); O[0][1] = fmaf(pa, v.y, O[0][1]);
            O[0][2] = fmaf(pa, v.z, O[0][2]); O[0][3] = fmaf(pa, v.w, O[0][3]);
            O[1][0] = fmaf(pb, v.x, O[1][0]); O[1][1] = fmaf(pb, v.y, O[1][1]);
            O[1][2] = fmaf(pb, v.z, O[1][2]); O[1][3] = fmaf(pb, v.w, O[1][3]);
            O[2][0] = fmaf(pc, v.x, O[2][0]); O[2][1] = fmaf(pc, v.y, O[2][1]);
            O[2][2] = fmaf(pc, v.z, O[2][2]); O[2][3] = fmaf(pc, v.w, O[2][3]);
            O[3][0] = fmaf(pd, v.x, O[3][0]); O[3][1] = fmaf(pd, v.y, O[3][1]);
            O[3][2] = fmaf(pd, v.z, O[3][2]); O[3][3] = fmaf(pd, v.w, O[3][3]);
        }
    }

    // ---- epilogue: normalize, gate, store (float4 along n) ----
    float inv_l[4];
    #pragma unroll
    for (int i = 0; i < 4; ++i) inv_l[i] = 1.0f / l_run[i];

    const float* Gb = Gw + ((size_t)b * kC) * kN;
    #pragma unroll
    for (int j = 0; j < 4; ++j) {
        const size_t chan = (size_t)(c4 + j);
        float4 g = *(const float4*)(Gb + chan * kN + n0 + r0);
        float4 res;
        res.x = O[0][j] * inv_l[0] * g.x;
        res.y = O[1][j] * inv_l[1] * g.y;
        res.z = O[2][j] * inv_l[2] * g.z;
        res.w = O[3][j] * inv_l[3] * g.w;
        *(float4*)(out + ((size_t)b * kC + chan) * kN + n0 + r0) = res;
    }
}

// ---------------------------------------------------------------------------
extern "C" void kernel_launch(void* const* d_in, const int* in_sizes, int n_in,
                              void* d_out, int out_size, void* d_ws, size_t ws_size,
                              hipStream_t stream) {
    const float* tgt   = (const float*)d_in[0];
    const float* ref   = (const float*)d_in[1];
    const float* W_tgt = (const float*)d_in[2];
    const float* b_tgt = (const float*)d_in[3];
    const float* W_ref = (const float*)d_in[4];
    const float* b_ref = (const float*)d_in[5];
    const float* W_out = (const float*)d_in[6];
    const float* b_out = (const float*)d_in[7];
    float* out = (float*)d_out;
    float* ws  = (float*)d_ws;

    const size_t M = 1024ull * 1024ull;
    float* Qw = ws;                 // 2M floats: [8][64][4096]
    float* Kw = ws + 2 * M;         // 2M floats
    float* Gw = ws + 4 * M;         // 4M floats: [8][128][4096]
    float* Vt = ws + 8 * M;         // 4M floats: [8][4096][128]
    const int use_vt = (ws_size >= 12ull * M * sizeof(float)) ? 1 : 0;

    proj_kernel<<<dim3(128, 2, 8), 256, 0, stream>>>(tgt, W_tgt, b_tgt, Qw, kCH, 1);
    proj_kernel<<<dim3(128, 2, 8), 256, 0, stream>>>(ref, W_ref, b_ref, Kw, kCH, 1);
    proj_kernel<<<dim3(128, 4, 8), 256, 0, stream>>>(tgt, W_out, b_out, Gw, kC, 0);
    if (use_vt)
        transpose_kernel<<<dim3(4096), 256, 0, stream>>>(ref, Vt);

    flash_kernel<<<dim3(1024), 256, 0, stream>>>(ref, Qw, Kw, Gw, Vt, out, use_vt);
}

// Round 3
// 420.887 us; speedup vs baseline: 3.6404x; 3.6404x over previous
//
#include <hip/hip_runtime.h>

typedef __attribute__((ext_vector_type(8))) short bf16x8;   // 8 bf16 = 4 VGPRs
typedef __attribute__((ext_vector_type(4))) float f32x4;

constexpr int kC  = 128;
constexpr int kCH = 64;
constexpr int kN  = 4096;
constexpr int kSD = 72;     // padded LDS stride (bf16 units): 144 B -> conflict-free

__device__ __forceinline__ unsigned short f2bf(float f) {
    unsigned u = __float_as_uint(f);
    u += 0x7FFF + ((u >> 16) & 1);            // round-to-nearest-even
    return (unsigned short)(u >> 16);
}
__device__ __forceinline__ float bf2f(unsigned short h) {
    return __uint_as_float((unsigned)h << 16);
}

// ---------------------------------------------------------------------------
// Gate projection: out = W.X + b (no relu), stored as bf16 hi+lo planes
// (g = hi + lo reconstructs ~fp32 precision; halves workspace vs fp32).
// Layout [b][128][n].
// ---------------------------------------------------------------------------
__global__ __launch_bounds__(256) void proj_gate_kernel(
    const float* __restrict__ X, const float* __restrict__ W,
    const float* __restrict__ bias,
    unsigned short* __restrict__ Gh, unsigned short* __restrict__ Gl)
{
    __shared__ float ws[32 * 129];
    const int t = threadIdx.x;
    const int mt = blockIdx.x, d0 = blockIdx.y * 32, b = blockIdx.z;
    for (int idx = t; idx < 32 * kC; idx += 256) {
        int dd = idx >> 7, c = idx & 127;
        ws[dd * 129 + c] = W[(size_t)(d0 + dd) * kC + c];
    }
    __syncthreads();
    const int m = mt * 32 + (t & 31);
    const int dl = t >> 5;
    const float* xp = X + ((size_t)b * kC) * kN + m;
    float acc[4];
    #pragma unroll
    for (int k = 0; k < 4; ++k) acc[k] = bias[d0 + dl + 8 * k];
    #pragma unroll 4
    for (int c = 0; c < kC; ++c) {
        float x = xp[(size_t)c * kN];
        #pragma unroll
        for (int k = 0; k < 4; ++k) acc[k] = fmaf(x, ws[(dl + 8 * k) * 129 + c], acc[k]);
    }
    #pragma unroll
    for (int k = 0; k < 4; ++k) {
        size_t idx = ((size_t)b * kC + d0 + dl + 8 * k) * kN + m;
        unsigned short h = f2bf(acc[k]);
        Gh[idx] = h;
        Gl[idx] = f2bf(acc[k] - bf2f(h));
    }
}

// ---------------------------------------------------------------------------
// Q/K projection: relu(W.X+b), output transposed, split hi/lo bf16:
// [b][n][64] d-contiguous (MFMA frags are ds_read_b128-able). LDS retranspose.
// ---------------------------------------------------------------------------
__global__ __launch_bounds__(256) void proj_qk_kernel(
    const float* __restrict__ X, const float* __restrict__ W,
    const float* __restrict__ bias,
    unsigned short* __restrict__ outH, unsigned short* __restrict__ outL)
{
    __shared__ float ws[32 * 129];
    __shared__ float tt[32 * 33];
    const int t = threadIdx.x;
    const int mt = blockIdx.x, d0 = blockIdx.y * 32, b = blockIdx.z;
    for (int idx = t; idx < 32 * kC; idx += 256) {
        int dd = idx >> 7, c = idx & 127;
        ws[dd * 129 + c] = W[(size_t)(d0 + dd) * kC + c];
    }
    __syncthreads();
    const int ml = t & 31;
    const int dl = t >> 5;
    const float* xp = X + ((size_t)b * kC) * kN + mt * 32 + ml;
    float acc[4];
    #pragma unroll
    for (int k = 0; k < 4; ++k) acc[k] = bias[d0 + dl + 8 * k];
    #pragma unroll 4
    for (int c = 0; c < kC; ++c) {
        float x = xp[(size_t)c * kN];
        #pragma unroll
        for (int k = 0; k < 4; ++k) acc[k] = fmaf(x, ws[(dl + 8 * k) * 129 + c], acc[k]);
    }
    #pragma unroll
    for (int k = 0; k < 4; ++k) tt[ml * 33 + dl + 8 * k] = fmaxf(acc[k], 0.0f);
    __syncthreads();
    const int mi = t >> 3, dj = (t & 7) * 4;
    unsigned short h[4], l[4];
    #pragma unroll
    for (int k = 0; k < 4; ++k) {
        float q = tt[mi * 33 + dj + k];
        h[k] = f2bf(q);
        l[k] = f2bf(q - bf2f(h[k]));
    }
    size_t base = ((size_t)(b * kN + mt * 32 + mi)) * kCH + d0 + dj;
    *(uint2*)(outH + base) = make_uint2((unsigned)h[0] | ((unsigned)h[1] << 16),
                                        (unsigned)h[2] | ((unsigned)h[3] << 16));
    *(uint2*)(outL + base) = make_uint2((unsigned)l[0] | ((unsigned)l[1] << 16),
                                        (unsigned)l[2] | ((unsigned)l[3] << 16));
}

// ---------------------------------------------------------------------------
// V convert: ref fp32 [b][c][n] -> bf16 same layout.
// ---------------------------------------------------------------------------
__global__ __launch_bounds__(256) void cvt_v_kernel(
    const float* __restrict__ in, unsigned short* __restrict__ out)
{
    const size_t i = (size_t)blockIdx.x * 256 + threadIdx.x;   // per float4
    float4 v = ((const float4*)in)[i];
    unsigned lo = (unsigned)f2bf(v.x) | ((unsigned)f2bf(v.y) << 16);
    unsigned hi = (unsigned)f2bf(v.z) | ((unsigned)f2bf(v.w) << 16);
    ((uint2*)out)[i] = make_uint2(lo, hi);
}

// ---------------------------------------------------------------------------
// Flash attention via MFMA 16x16x32 bf16, computing S^T = K.Q^T.
// Compensated QK^T: S = Kh.Qh + Kl.Qh + Kh.Ql (lo.lo dropped) -> ~fp32 S,
// so exp() sees negligible input error. l_run accumulated from the
// bf16-ROUNDED p values so the softmax denominator matches PV's numerator.
// Block: 4 waves x 16 Q-rows = 64 rows; key tile 64; 512 blocks (b = blk&7).
// Register double-buffer prefetch for K/V tiles. LDS 64.5 KB -> 2 blocks/CU.
// ---------------------------------------------------------------------------
__global__ __launch_bounds__(256, 2) void flash2_kernel(
    const unsigned short* __restrict__ Qh,   // [8][4096][64] bf16 hi
    const unsigned short* __restrict__ Ql,   // [8][4096][64] bf16 lo
    const unsigned short* __restrict__ Kh,   // [8][4096][64] bf16 hi
    const unsigned short* __restrict__ Kl,   // [8][4096][64] bf16 lo
    const unsigned short* __restrict__ Vw,   // [8][128][4096] bf16
    const unsigned short* __restrict__ Gh,   // [8][128][4096] bf16 hi
    const unsigned short* __restrict__ Gl,   // [8][128][4096] bf16 lo
    float* __restrict__ out)                 // [8][128][4096]
{
    __shared__ __align__(16) unsigned short Qsh[64 * kSD];
    __shared__ __align__(16) unsigned short Qsl[64 * kSD];
    __shared__ __align__(16) unsigned short Ksh[64 * kSD];
    __shared__ __align__(16) unsigned short Ksl[64 * kSD];
    __shared__ __align__(16) unsigned short Vs[128 * kSD];
    __shared__ __align__(16) unsigned short Ps[64 * kSD];

    const int t = threadIdx.x;
    const int b = blockIdx.x & 7;
    const int n0 = (blockIdx.x >> 3) << 6;
    const int w = t >> 6, lane = t & 63;
    const int lg = lane >> 4, lm = lane & 15;
    const int row_q = w * 16 + lm;

    const unsigned short* Qhb = Qh + ((size_t)b << 12) * kCH;
    const unsigned short* Qlb = Ql + ((size_t)b << 12) * kCH;
    const unsigned short* Khb = Kh + ((size_t)b << 12) * kCH;
    const unsigned short* Klb = Kl + ((size_t)b << 12) * kCH;
    const unsigned short* Vb  = Vw + ((size_t)b << 7) * (size_t)kN;

    const int srow = t >> 3;                 // 0..31
    const int sdg  = (t & 7) << 3;           // 0..56 (bf16 units, 16B groups)

    // ---- stage Q hi+lo (once) ----
    #pragma unroll
    for (int h = 0; h < 2; ++h) {
        *(uint4*)(Qsh + (srow + 32 * h) * kSD + sdg) =
            *(const uint4*)(Qhb + (size_t)(n0 + srow + 32 * h) * kCH + sdg);
        *(uint4*)(Qsl + (srow + 32 * h) * kSD + sdg) =
            *(const uint4*)(Qlb + (size_t)(n0 + srow + 32 * h) * kCH + sdg);
    }

    f32x4 O[8];
    #pragma unroll
    for (int cb = 0; cb < 8; ++cb) O[cb] = (f32x4){0.f, 0.f, 0.f, 0.f};
    float m_run = -3.0e38f, l_run = 0.0f;

    uint4 kpfh[2], kpfl[2], vpf[4];
    auto loadT = [&](int m0) {
        kpfh[0] = *(const uint4*)(Khb + (size_t)(m0 + srow)      * kCH + sdg);
        kpfh[1] = *(const uint4*)(Khb + (size_t)(m0 + srow + 32) * kCH + sdg);
        kpfl[0] = *(const uint4*)(Klb + (size_t)(m0 + srow)      * kCH + sdg);
        kpfl[1] = *(const uint4*)(Klb + (size_t)(m0 + srow + 32) * kCH + sdg);
        #pragma unroll
        for (int k4 = 0; k4 < 4; ++k4)
            vpf[k4] = *(const uint4*)(Vb + (size_t)(k4 * 32 + srow) * kN + m0 + sdg);
    };
    auto writeT = [&]() {
        *(uint4*)(Ksh + (srow)      * kSD + sdg) = kpfh[0];
        *(uint4*)(Ksh + (srow + 32) * kSD + sdg) = kpfh[1];
        *(uint4*)(Ksl + (srow)      * kSD + sdg) = kpfl[0];
        *(uint4*)(Ksl + (srow + 32) * kSD + sdg) = kpfl[1];
        #pragma unroll
        for (int k4 = 0; k4 < 4; ++k4)
            *(uint4*)(Vs + (k4 * 32 + srow) * kSD + sdg) = vpf[k4];
    };

    loadT(0);
    writeT();

    for (int kt = 0; kt < kN / 64; ++kt) {
        __syncthreads();
        if (kt < kN / 64 - 1) loadT((kt + 1) << 6);   // prefetch next tile

        // ---- compensated QK^T -> S^T ----
        bf16x8 qh0 = *(const bf16x8*)(Qsh + row_q * kSD +      (lg << 3));
        bf16x8 qh1 = *(const bf16x8*)(Qsh + row_q * kSD + 32 + (lg << 3));
        bf16x8 ql0 = *(const bf16x8*)(Qsl + row_q * kSD +      (lg << 3));
        bf16x8 ql1 = *(const bf16x8*)(Qsl + row_q * kSD + 32 + (lg << 3));
        f32x4 s[4];
        #pragma unroll
        for (int mb = 0; mb < 4; ++mb) {
            const unsigned short* krh = Ksh + (mb * 16 + lm) * kSD + (lg << 3);
            const unsigned short* krl = Ksl + (mb * 16 + lm) * kSD + (lg << 3);
            bf16x8 kh0 = *(const bf16x8*)(krh);
            bf16x8 kh1 = *(const bf16x8*)(krh + 32);
            bf16x8 kl0 = *(const bf16x8*)(krl);
            bf16x8 kl1 = *(const bf16x8*)(krl + 32);
            f32x4 acc = (f32x4){0.f, 0.f, 0.f, 0.f};
            acc = __builtin_amdgcn_mfma_f32_16x16x32_bf16(kl0, qh0, acc, 0, 0, 0);
            acc = __builtin_amdgcn_mfma_f32_16x16x32_bf16(kl1, qh1, acc, 0, 0, 0);
            acc = __builtin_amdgcn_mfma_f32_16x16x32_bf16(kh0, ql0, acc, 0, 0, 0);
            acc = __builtin_amdgcn_mfma_f32_16x16x32_bf16(kh1, ql1, acc, 0, 0, 0);
            acc = __builtin_amdgcn_mfma_f32_16x16x32_bf16(kh0, qh0, acc, 0, 0, 0);
            acc = __builtin_amdgcn_mfma_f32_16x16x32_bf16(kh1, qh1, acc, 0, 0, 0);
            s[mb] = acc;
        }

        // ---- online softmax for row lm; lane holds keys mb*16 + lg*4 + r ----
        float mloc = -3.0e38f;
        #pragma unroll
        for (int mb = 0; mb < 4; ++mb)
            #pragma unroll
            for (int r = 0; r < 4; ++r) mloc = fmaxf(mloc, s[mb][r]);
        mloc = fmaxf(mloc, __shfl_xor(mloc, 16, 64));
        mloc = fmaxf(mloc, __shfl_xor(mloc, 32, 64));
        float mnew = fmaxf(m_run, mloc);
        float alpha = __expf(m_run - mnew);
        float psum = 0.0f;
        #pragma unroll
        for (int mb = 0; mb < 4; ++mb) {
            unsigned short h0 = f2bf(__expf(s[mb][0] - mnew));
            unsigned short h1 = f2bf(__expf(s[mb][1] - mnew));
            unsigned short h2 = f2bf(__expf(s[mb][2] - mnew));
            unsigned short h3 = f2bf(__expf(s[mb][3] - mnew));
            // denominator from the ROUNDED p's -> matches PV numerator exactly
            psum += (bf2f(h0) + bf2f(h1)) + (bf2f(h2) + bf2f(h3));
            uint2 pk;
            pk.x = (unsigned)h0 | ((unsigned)h1 << 16);
            pk.y = (unsigned)h2 | ((unsigned)h3 << 16);
            *(uint2*)(Ps + row_q * kSD + mb * 16 + (lg << 2)) = pk;
        }
        psum += __shfl_xor(psum, 16, 64);
        psum += __shfl_xor(psum, 32, 64);
        l_run = l_run * alpha + psum;
        m_run = mnew;

        // rescale O: O-frag rows are lg*4+r; alpha lives at lane (row)
        float a0 = __shfl(alpha, (lg << 2) + 0, 64);
        float a1 = __shfl(alpha, (lg << 2) + 1, 64);
        float a2 = __shfl(alpha, (lg << 2) + 2, 64);
        float a3 = __shfl(alpha, (lg << 2) + 3, 64);
        #pragma unroll
        for (int cb = 0; cb < 8; ++cb) {
            O[cb][0] *= a0; O[cb][1] *= a1; O[cb][2] *= a2; O[cb][3] *= a3;
        }

        // ---- PV: A=P[row][key], B=V[c][key] ----
        bf16x8 pf0 = *(const bf16x8*)(Ps + row_q * kSD +      (lg << 3));
        bf16x8 pf1 = *(const bf16x8*)(Ps + row_q * kSD + 32 + (lg << 3));
        #pragma unroll
        for (int cb = 0; cb < 8; ++cb) {
            const unsigned short* vr = Vs + (cb * 16 + lm) * kSD + (lg << 3);
            bf16x8 vf0 = *(const bf16x8*)(vr);
            bf16x8 vf1 = *(const bf16x8*)(vr + 32);
            O[cb] = __builtin_amdgcn_mfma_f32_16x16x32_bf16(pf0, vf0, O[cb], 0, 0, 0);
            O[cb] = __builtin_amdgcn_mfma_f32_16x16x32_bf16(pf1, vf1, O[cb], 0, 0, 0);
        }

        __syncthreads();
        if (kt < kN / 64 - 1) writeT();
    }

    // ---- epilogue: normalize, gate (hi+lo reconstruct), store float4 ----
    float inv = 1.0f / l_run;
    float i0 = __shfl(inv, (lg << 2) + 0, 64);
    float i1 = __shfl(inv, (lg << 2) + 1, 64);
    float i2 = __shfl(inv, (lg << 2) + 2, 64);
    float i3 = __shfl(inv, (lg << 2) + 3, 64);
    const unsigned short* Ghb = Gh + ((size_t)b << 7) * kN;
    const unsigned short* Glb = Gl + ((size_t)b << 7) * kN;
    float* Ob = out + ((size_t)b << 7) * kN;
    #pragma unroll
    for (int cb = 0; cb < 8; ++cb) {
        int c = cb * 16 + lm;
        size_t base = (size_t)c * kN + n0 + w * 16 + (lg << 2);
        ushort4 gh = *(const ushort4*)(Ghb + base);
        ushort4 gl = *(const ushort4*)(Glb + base);
        float4 res;
        res.x = O[cb][0] * i0 * (bf2f(gh.x) + bf2f(gl.x));
        res.y = O[cb][1] * i1 * (bf2f(gh.y) + bf2f(gl.y));
        res.z = O[cb][2] * i2 * (bf2f(gh.z) + bf2f(gl.z));
        res.w = O[cb][3] * i3 * (bf2f(gh.w) + bf2f(gl.w));
        *(float4*)(Ob + base) = res;
    }
}

// ---------------------------------------------------------------------------
extern "C" void kernel_launch(void* const* d_in, const int* in_sizes, int n_in,
                              void* d_out, int out_size, void* d_ws, size_t ws_size,
                              hipStream_t stream) {
    const float* tgt   = (const float*)d_in[0];
    const float* ref   = (const float*)d_in[1];
    const float* W_tgt = (const float*)d_in[2];
    const float* b_tgt = (const float*)d_in[3];
    const float* W_ref = (const float*)d_in[4];
    const float* b_ref = (const float*)d_in[5];
    const float* W_out = (const float*)d_in[6];
    const float* b_out = (const float*)d_in[7];
    float* out = (float*)d_out;

    const size_t QK = (size_t)8 * kN * kCH;              // 2M elems = 4 MB each
    const size_t CV = (size_t)8 * kC * kN;               // 4M elems
    unsigned short* Qh = (unsigned short*)d_ws;          // 4 MB
    unsigned short* Ql = Qh + QK;                        // 4 MB
    unsigned short* Kh = Ql + QK;                        // 4 MB
    unsigned short* Kl = Kh + QK;                        // 4 MB
    unsigned short* Vw = Kl + QK;                        // 8 MB
    unsigned short* Gh = Vw + CV;                        // 8 MB
    unsigned short* Gl = Gh + CV;                        // 8 MB  (total 32 MB)

    proj_qk_kernel <<<dim3(128, 2, 8), 256, 0, stream>>>(tgt, W_tgt, b_tgt, Qh, Ql);
    proj_qk_kernel <<<dim3(128, 2, 8), 256, 0, stream>>>(ref, W_ref, b_ref, Kh, Kl);
    proj_gate_kernel<<<dim3(128, 4, 8), 256, 0, stream>>>(tgt, W_out, b_out, Gh, Gl);
    cvt_v_kernel   <<<dim3((8 * kC * kN) / 4 / 256), 256, 0, stream>>>(ref, Vw);

    flash2_kernel<<<dim3(512), 256, 0, stream>>>(Qh, Ql, Kh, Kl, Vw, Gh, Gl, out);
}

// Round 4
// 419.216 us; speedup vs baseline: 3.6549x; 1.0040x over previous
//
#include <hip/hip_runtime.h>

typedef __attribute__((ext_vector_type(8))) _Float16 f16x8;   // 8 fp16 = 4 VGPRs
typedef __attribute__((ext_vector_type(4))) float f32x4;

constexpr int kC  = 128;
constexpr int kCH = 64;
constexpr int kN  = 4096;

__device__ __forceinline__ unsigned short f2h(float f) {
    union { _Float16 h; unsigned short u; } cv;
    cv.h = (_Float16)f;
    return cv.u;
}
__device__ __forceinline__ float h2f(unsigned short u) {
    union { _Float16 h; unsigned short u; } cv;
    cv.u = u;
    return (float)cv.h;
}

// ---------------------------------------------------------------------------
// Gate projection (fp32 out, layout [b][128][n]) — R1-validated kernel.
// ---------------------------------------------------------------------------
__global__ __launch_bounds__(256) void proj_kernel(
    const float* __restrict__ X, const float* __restrict__ W,
    const float* __restrict__ bias, float* __restrict__ out, int OC, int do_relu)
{
    __shared__ float ws[32 * 129];
    const int t = threadIdx.x;
    const int mt = blockIdx.x, d0 = blockIdx.y * 32, b = blockIdx.z;
    for (int idx = t; idx < 32 * kC; idx += 256) {
        int dd = idx >> 7, c = idx & 127;
        ws[dd * 129 + c] = W[(size_t)(d0 + dd) * kC + c];
    }
    __syncthreads();
    const int m = mt * 32 + (t & 31);
    const int dl = t >> 5;
    const float* xp = X + ((size_t)b * kC) * kN + m;
    float acc[4];
    #pragma unroll
    for (int k = 0; k < 4; ++k) acc[k] = bias[d0 + dl + 8 * k];
    #pragma unroll 4
    for (int c = 0; c < kC; ++c) {
        float x = xp[(size_t)c * kN];
        #pragma unroll
        for (int k = 0; k < 4; ++k) acc[k] = fmaf(x, ws[(dl + 8 * k) * 129 + c], acc[k]);
    }
    #pragma unroll
    for (int k = 0; k < 4; ++k) {
        float v = do_relu ? fmaxf(acc[k], 0.0f) : acc[k];
        out[((size_t)b * OC + d0 + dl + 8 * k) * kN + m] = v;
    }
}

// ---------------------------------------------------------------------------
// Q/K projection: relu(W.X+b), fp16, transposed [b][n][64] (d-contiguous).
// ---------------------------------------------------------------------------
__global__ __launch_bounds__(256) void proj_qk_f16(
    const float* __restrict__ X, const float* __restrict__ W,
    const float* __restrict__ bias, unsigned short* __restrict__ outT)
{
    __shared__ float ws[32 * 129];
    __shared__ float tt[32 * 33];
    const int t = threadIdx.x;
    const int mt = blockIdx.x, d0 = blockIdx.y * 32, b = blockIdx.z;
    for (int idx = t; idx < 32 * kC; idx += 256) {
        int dd = idx >> 7, c = idx & 127;
        ws[dd * 129 + c] = W[(size_t)(d0 + dd) * kC + c];
    }
    __syncthreads();
    const int ml = t & 31;
    const int dl = t >> 5;
    const float* xp = X + ((size_t)b * kC) * kN + mt * 32 + ml;
    float acc[4];
    #pragma unroll
    for (int k = 0; k < 4; ++k) acc[k] = bias[d0 + dl + 8 * k];
    #pragma unroll 4
    for (int c = 0; c < kC; ++c) {
        float x = xp[(size_t)c * kN];
        #pragma unroll
        for (int k = 0; k < 4; ++k) acc[k] = fmaf(x, ws[(dl + 8 * k) * 129 + c], acc[k]);
    }
    #pragma unroll
    for (int k = 0; k < 4; ++k) tt[ml * 33 + dl + 8 * k] = fmaxf(acc[k], 0.0f);
    __syncthreads();
    const int mi = t >> 3, dj = (t & 7) * 4;
    unsigned lo = (unsigned)f2h(tt[mi * 33 + dj + 0]) | ((unsigned)f2h(tt[mi * 33 + dj + 1]) << 16);
    unsigned hi = (unsigned)f2h(tt[mi * 33 + dj + 2]) | ((unsigned)f2h(tt[mi * 33 + dj + 3]) << 16);
    *(uint2*)(outT + ((size_t)(b * kN + mt * 32 + mi)) * kCH + d0 + dj) = make_uint2(lo, hi);
}

// ---------------------------------------------------------------------------
// V convert: ref fp32 [b][c][n] -> fp16 same layout.
// ---------------------------------------------------------------------------
__global__ __launch_bounds__(256) void cvt_v_f16(
    const float* __restrict__ in, unsigned short* __restrict__ out)
{
    const size_t i = (size_t)blockIdx.x * 256 + threadIdx.x;   // per float4
    float4 v = ((const float4*)in)[i];
    unsigned lo = (unsigned)f2h(v.x) | ((unsigned)f2h(v.y) << 16);
    unsigned hi = (unsigned)f2h(v.z) | ((unsigned)f2h(v.w) << 16);
    ((uint2*)out)[i] = make_uint2(lo, hi);
}

// ---------------------------------------------------------------------------
// Flash attention, fp16 MFMA 16x16x32, S^T = K.Q^T formulation.
// - Single-term fp16 QK (10 mantissa bits -> ~16x less S error than bf16).
// - Q fragments live in registers (loaded once from global; no Qs LDS).
// - Key tiles processed in PAIRS (128 keys/iter): one softmax per pair ->
//   half the barriers, double the ILP in the reduce/exp chains.
// - LDS rows 128 B, XOR swizzle (16B-chunk ^= row&7) instead of padding.
// - l_run accumulated from fp16-ROUNDED p's (matches PV numerator).
// Block: 4 waves x 16 rows = 64 rows; 512 blocks (b = blk&7). LDS 56 KB.
// ---------------------------------------------------------------------------
__global__ __launch_bounds__(256, 2) void flash3_kernel(
    const unsigned short* __restrict__ Qw,   // [8][4096][64] fp16
    const unsigned short* __restrict__ Kw,   // [8][4096][64] fp16
    const unsigned short* __restrict__ Vw,   // [8][128][4096] fp16
    const float* __restrict__ Gw,            // [8][128][4096] fp32 gate
    float* __restrict__ out)                 // [8][128][4096]
{
    __shared__ __align__(16) unsigned short Ks[2][64 * 64];
    __shared__ __align__(16) unsigned short Vs[2][128 * 64];
    __shared__ __align__(16) unsigned short Ps[64 * 64];

    const int t = threadIdx.x;
    const int b = blockIdx.x & 7;
    const int n0 = (blockIdx.x >> 3) << 6;
    const int w = t >> 6, lane = t & 63;
    const int lg = (lane >> 4) & 3, lm = lane & 15;
    const int row_q = w * 16 + lm;
    const int swz = lm & 7;

    const unsigned short* Qb = Qw + ((size_t)b * kN) * kCH;
    const unsigned short* Kb = Kw + ((size_t)b * kN) * kCH;
    const unsigned short* Vb = Vw + ((size_t)b * kC) * kN;

    // ---- Q fragments: load once from global, keep in registers ----
    f16x8 qf0 = *(const f16x8*)(Qb + (size_t)(n0 + row_q) * kCH + (lg << 3));
    f16x8 qf1 = *(const f16x8*)(Qb + (size_t)(n0 + row_q) * kCH + 32 + (lg << 3));

    // ---- precomputed LDS offsets (shorts), all loop-invariant ----
    const int stg_row = t >> 3;              // 0..31
    const int stg_chk = t & 7;
    const int koff = stg_row * 64 + ((stg_chk ^ (stg_row & 7)) << 3);   // (row+32)&7 == row&7
    int voff[4];
    #pragma unroll
    for (int k4 = 0; k4 < 4; ++k4)
        voff[k4] = (k4 * 32 + stg_row) * 64 + ((stg_chk ^ (stg_row & 7)) << 3);
    const int fswz0 = ((lg ^ swz) << 3);          // frag chunk lg
    const int fswz1 = (((4 | lg) ^ swz) << 3);    // frag chunk 4+lg
    int psw[4];
    #pragma unroll
    for (int mb = 0; mb < 4; ++mb)
        psw[mb] = row_q * 64 + (((2 * mb + (lg >> 1)) ^ swz) << 3) + ((lg & 1) << 2);

    f32x4 O[8];
    #pragma unroll
    for (int cb = 0; cb < 8; ++cb) O[cb] = (f32x4){0.f, 0.f, 0.f, 0.f};
    float m_run = -3.0e38f, l_run = 0.0f;

    uint4 kpf[2][2], vpf[2][4];
    auto loadPair = [&](int p) {
        #pragma unroll
        for (int tau = 0; tau < 2; ++tau) {
            const int m0 = (p << 7) + (tau << 6);
            kpf[tau][0] = *(const uint4*)(Kb + (size_t)(m0 + stg_row) * kCH + (stg_chk << 3));
            kpf[tau][1] = *(const uint4*)(Kb + (size_t)(m0 + stg_row + 32) * kCH + (stg_chk << 3));
            #pragma unroll
            for (int k4 = 0; k4 < 4; ++k4)
                vpf[tau][k4] = *(const uint4*)(Vb + (size_t)(k4 * 32 + stg_row) * kN + m0 + (stg_chk << 3));
        }
    };
    auto writePair = [&]() {
        #pragma unroll
        for (int tau = 0; tau < 2; ++tau) {
            *(uint4*)(Ks[tau] + koff)           = kpf[tau][0];
            *(uint4*)(Ks[tau] + koff + 32 * 64) = kpf[tau][1];
            #pragma unroll
            for (int k4 = 0; k4 < 4; ++k4)
                *(uint4*)(Vs[tau] + voff[k4]) = vpf[tau][k4];
        }
    };

    loadPair(0);
    writePair();

    for (int p = 0; p < kN / 128; ++p) {
        __syncthreads();                     // staged pair visible
        if (p < kN / 128 - 1) loadPair(p + 1);   // global prefetch (regs)

        // ---- QK^T -> S^T for both tiles of the pair ----
        f32x4 s[2][4];
        #pragma unroll
        for (int tau = 0; tau < 2; ++tau) {
            #pragma unroll
            for (int mb = 0; mb < 4; ++mb) {
                const unsigned short* kr = Ks[tau] + (mb << 10) + (lm << 6);
                f16x8 kf0 = *(const f16x8*)(kr + fswz0);
                f16x8 kf1 = *(const f16x8*)(kr + fswz1);
                f32x4 acc = (f32x4){0.f, 0.f, 0.f, 0.f};
                acc = __builtin_amdgcn_mfma_f32_16x16x32_f16(kf0, qf0, acc, 0, 0, 0);
                acc = __builtin_amdgcn_mfma_f32_16x16x32_f16(kf1, qf1, acc, 0, 0, 0);
                s[tau][mb] = acc;
            }
        }

        // ---- joint online softmax over 128 keys (row = lm) ----
        float mloc = -3.0e38f;
        #pragma unroll
        for (int tau = 0; tau < 2; ++tau)
            #pragma unroll
            for (int mb = 0; mb < 4; ++mb)
                #pragma unroll
                for (int r = 0; r < 4; ++r) mloc = fmaxf(mloc, s[tau][mb][r]);
        mloc = fmaxf(mloc, __shfl_xor(mloc, 16, 64));
        mloc = fmaxf(mloc, __shfl_xor(mloc, 32, 64));
        float mnew = fmaxf(m_run, mloc);
        float alpha = __expf(m_run - mnew);

        uint2 ph[2][4];
        float psum = 0.0f;
        #pragma unroll
        for (int tau = 0; tau < 2; ++tau) {
            #pragma unroll
            for (int mb = 0; mb < 4; ++mb) {
                unsigned short h0 = f2h(__expf(s[tau][mb][0] - mnew));
                unsigned short h1 = f2h(__expf(s[tau][mb][1] - mnew));
                unsigned short h2 = f2h(__expf(s[tau][mb][2] - mnew));
                unsigned short h3 = f2h(__expf(s[tau][mb][3] - mnew));
                psum += (h2f(h0) + h2f(h1)) + (h2f(h2) + h2f(h3));
                ph[tau][mb] = make_uint2((unsigned)h0 | ((unsigned)h1 << 16),
                                         (unsigned)h2 | ((unsigned)h3 << 16));
            }
        }
        psum += __shfl_xor(psum, 16, 64);
        psum += __shfl_xor(psum, 32, 64);
        l_run = l_run * alpha + psum;
        m_run = mnew;

        // rescale O (rows of O-frag are tokens lg*4+r; alpha lives at lane==row)
        float a0 = __shfl(alpha, (lg << 2) + 0, 64);
        float a1 = __shfl(alpha, (lg << 2) + 1, 64);
        float a2 = __shfl(alpha, (lg << 2) + 2, 64);
        float a3 = __shfl(alpha, (lg << 2) + 3, 64);
        #pragma unroll
        for (int cb = 0; cb < 8; ++cb) {
            O[cb][0] *= a0; O[cb][1] *= a1; O[cb][2] *= a2; O[cb][3] *= a3;
        }

        // ---- PV per tile (Ps reused; same-wave ordering via lgkmcnt) ----
        #pragma unroll
        for (int tau = 0; tau < 2; ++tau) {
            #pragma unroll
            for (int mb = 0; mb < 4; ++mb)
                *(uint2*)(Ps + psw[mb]) = ph[tau][mb];
            f16x8 pf0 = *(const f16x8*)(Ps + row_q * 64 + fswz0);
            f16x8 pf1 = *(const f16x8*)(Ps + row_q * 64 + fswz1);
            #pragma unroll
            for (int cb = 0; cb < 8; ++cb) {
                const unsigned short* vr = Vs[tau] + ((cb * 16 + lm) << 6);
                f16x8 vf0 = *(const f16x8*)(vr + fswz0);
                f16x8 vf1 = *(const f16x8*)(vr + fswz1);
                O[cb] = __builtin_amdgcn_mfma_f32_16x16x32_f16(pf0, vf0, O[cb], 0, 0, 0);
                O[cb] = __builtin_amdgcn_mfma_f32_16x16x32_f16(pf1, vf1, O[cb], 0, 0, 0);
            }
        }

        __syncthreads();                     // all reads of this pair done
        if (p < kN / 128 - 1) writePair();   // commit prefetched pair
    }

    // ---- epilogue: normalize, gate, store float4 (reg-quad = 4 tokens) ----
    float inv = 1.0f / l_run;
    float i0 = __shfl(inv, (lg << 2) + 0, 64);
    float i1 = __shfl(inv, (lg << 2) + 1, 64);
    float i2 = __shfl(inv, (lg << 2) + 2, 64);
    float i3 = __shfl(inv, (lg << 2) + 3, 64);
    const float* Gb = Gw + ((size_t)b * kC) * kN;
    float* Ob = out + ((size_t)b * kC) * kN;
    #pragma unroll
    for (int cb = 0; cb < 8; ++cb) {
        int c = cb * 16 + lm;
        size_t base = (size_t)c * kN + n0 + w * 16 + (lg << 2);
        float4 g = *(const float4*)(Gb + base);
        float4 res;
        res.x = O[cb][0] * i0 * g.x;
        res.y = O[cb][1] * i1 * g.y;
        res.z = O[cb][2] * i2 * g.z;
        res.w = O[cb][3] * i3 * g.w;
        *(float4*)(Ob + base) = res;
    }
}

// ---------------------------------------------------------------------------
extern "C" void kernel_launch(void* const* d_in, const int* in_sizes, int n_in,
                              void* d_out, int out_size, void* d_ws, size_t ws_size,
                              hipStream_t stream) {
    const float* tgt   = (const float*)d_in[0];
    const float* ref   = (const float*)d_in[1];
    const float* W_tgt = (const float*)d_in[2];
    const float* b_tgt = (const float*)d_in[3];
    const float* W_ref = (const float*)d_in[4];
    const float* b_ref = (const float*)d_in[5];
    const float* W_out = (const float*)d_in[6];
    const float* b_out = (const float*)d_in[7];
    float* out = (float*)d_out;

    const size_t QK = (size_t)8 * kN * kCH;              // 2M elems (fp16 -> 4 MB)
    const size_t CV = (size_t)8 * kC * kN;               // 4M elems (fp16 -> 8 MB)
    unsigned short* Qw = (unsigned short*)d_ws;          // 4 MB
    unsigned short* Kw = Qw + QK;                        // 4 MB
    unsigned short* Vw = Kw + QK;                        // 8 MB
    float*          Gw = (float*)(Vw + CV);              // 16 MB (total 32 MB)

    proj_qk_f16<<<dim3(128, 2, 8), 256, 0, stream>>>(tgt, W_tgt, b_tgt, Qw);
    proj_qk_f16<<<dim3(128, 2, 8), 256, 0, stream>>>(ref, W_ref, b_ref, Kw);
    proj_kernel<<<dim3(128, 4, 8), 256, 0, stream>>>(tgt, W_out, b_out, Gw, kC, 0);
    cvt_v_f16  <<<dim3((8 * kC * kN) / 4 / 256), 256, 0, stream>>>(ref, Vw);

    flash3_kernel<<<dim3(512), 256, 0, stream>>>(Qw, Kw, Vw, Gw, out);
}

// Round 5
// 242.019 us; speedup vs baseline: 6.3309x; 1.7322x over previous
//
#include <hip/hip_runtime.h>

typedef __attribute__((ext_vector_type(8))) _Float16 f16x8;   // 8 fp16 = 4 VGPRs
typedef __attribute__((ext_vector_type(4))) float f32x4;

constexpr int kC  = 128;
constexpr int kCH = 64;
constexpr int kN  = 4096;

__device__ __forceinline__ unsigned short f2h(float f) {
    union { _Float16 h; unsigned short u; } cv;
    cv.h = (_Float16)f;
    return cv.u;
}
__device__ __forceinline__ float h2f(unsigned short u) {
    union { _Float16 h; unsigned short u; } cv;
    cv.u = u;
    return (float)cv.h;
}

// ---------------------------------------------------------------------------
// Q/K projection (fused): relu(W.X+b) -> fp16, transposed [b][n][64].
// Thread = 8 tokens x 4 channels; W^T in LDS (stride 33, b128 reads).
// grid (16 tokblk, 2 chblk, 16: b=z&7, sel=z>>3)
// ---------------------------------------------------------------------------
__global__ __launch_bounds__(256) void proj_qk2(
    const float* __restrict__ tgt, const float* __restrict__ ref,
    const float* __restrict__ Wt, const float* __restrict__ Wr,
    const float* __restrict__ bt, const float* __restrict__ br,
    unsigned short* __restrict__ Qw, unsigned short* __restrict__ Kw)
{
    __shared__ float wt[128 * 33];
    const int t = threadIdx.x;
    const int b = blockIdx.z & 7, sel = blockIdx.z >> 3;
    const float* X    = sel ? ref : tgt;
    const float* W    = sel ? Wr : Wt;
    const float* bias = sel ? br : bt;
    unsigned short* out = sel ? Kw : Qw;
    const int ch0  = blockIdx.y * 32;
    const int tok0 = blockIdx.x * 256 + (t >> 3) * 8;
    const int cg   = t & 7;

    #pragma unroll
    for (int k = 0; k < 16; ++k) {
        int i = t + k * 256;                  // 0..4095
        int oc = i >> 7, c = i & 127;
        wt[c * 33 + oc] = W[(size_t)(ch0 + oc) * kC + c];
    }
    __syncthreads();

    float bv[4];
    #pragma unroll
    for (int j = 0; j < 4; ++j) bv[j] = bias[ch0 + cg * 4 + j];
    float acc[8][4];
    #pragma unroll
    for (int i = 0; i < 8; ++i)
        #pragma unroll
        for (int j = 0; j < 4; ++j) acc[i][j] = bv[j];

    const float* Xb = X + ((size_t)b * kC) * kN + tok0;
    #pragma unroll 2
    for (int c = 0; c < kC; ++c) {
        float4 x0 = *(const float4*)(Xb + (size_t)c * kN);
        float4 x1 = *(const float4*)(Xb + (size_t)c * kN + 4);
        float4 wv = *(const float4*)(wt + c * 33 + cg * 4);
        float xx[8] = {x0.x, x0.y, x0.z, x0.w, x1.x, x1.y, x1.z, x1.w};
        float ww[4] = {wv.x, wv.y, wv.z, wv.w};
        #pragma unroll
        for (int i = 0; i < 8; ++i)
            #pragma unroll
            for (int j = 0; j < 4; ++j) acc[i][j] = fmaf(xx[i], ww[j], acc[i][j]);
    }

    #pragma unroll
    for (int i = 0; i < 8; ++i) {
        unsigned short h0 = f2h(fmaxf(acc[i][0], 0.0f));
        unsigned short h1 = f2h(fmaxf(acc[i][1], 0.0f));
        unsigned short h2 = f2h(fmaxf(acc[i][2], 0.0f));
        unsigned short h3 = f2h(fmaxf(acc[i][3], 0.0f));
        *(uint2*)(out + ((size_t)b * kN + tok0 + i) * kCH + ch0 + cg * 4) =
            make_uint2((unsigned)h0 | ((unsigned)h1 << 16),
                       (unsigned)h2 | ((unsigned)h3 << 16));
    }
}

// ---------------------------------------------------------------------------
// Gate projection: W.X + b (no relu), fp32 [b][128][n]. Same blocking.
// grid (16, 4, 8)
// ---------------------------------------------------------------------------
__global__ __launch_bounds__(256) void proj_gate2(
    const float* __restrict__ X, const float* __restrict__ W,
    const float* __restrict__ bias, float* __restrict__ Gw)
{
    __shared__ float wt[128 * 33];
    const int t = threadIdx.x;
    const int b = blockIdx.z;
    const int ch0  = blockIdx.y * 32;
    const int tok0 = blockIdx.x * 256 + (t >> 3) * 8;
    const int cg   = t & 7;

    #pragma unroll
    for (int k = 0; k < 16; ++k) {
        int i = t + k * 256;
        int oc = i >> 7, c = i & 127;
        wt[c * 33 + oc] = W[(size_t)(ch0 + oc) * kC + c];
    }
    __syncthreads();

    float bv[4];
    #pragma unroll
    for (int j = 0; j < 4; ++j) bv[j] = bias[ch0 + cg * 4 + j];
    float acc[8][4];
    #pragma unroll
    for (int i = 0; i < 8; ++i)
        #pragma unroll
        for (int j = 0; j < 4; ++j) acc[i][j] = bv[j];

    const float* Xb = X + ((size_t)b * kC) * kN + tok0;
    #pragma unroll 2
    for (int c = 0; c < kC; ++c) {
        float4 x0 = *(const float4*)(Xb + (size_t)c * kN);
        float4 x1 = *(const float4*)(Xb + (size_t)c * kN + 4);
        float4 wv = *(const float4*)(wt + c * 33 + cg * 4);
        float xx[8] = {x0.x, x0.y, x0.z, x0.w, x1.x, x1.y, x1.z, x1.w};
        float ww[4] = {wv.x, wv.y, wv.z, wv.w};
        #pragma unroll
        for (int i = 0; i < 8; ++i)
            #pragma unroll
            for (int j = 0; j < 4; ++j) acc[i][j] = fmaf(xx[i], ww[j], acc[i][j]);
    }

    #pragma unroll
    for (int j = 0; j < 4; ++j) {
        size_t base = ((size_t)b * kC + ch0 + cg * 4 + j) * kN + tok0;
        *(float4*)(Gw + base)     = make_float4(acc[0][j], acc[1][j], acc[2][j], acc[3][j]);
        *(float4*)(Gw + base + 4) = make_float4(acc[4][j], acc[5][j], acc[6][j], acc[7][j]);
    }
}

// ---------------------------------------------------------------------------
// V convert: ref fp32 [b][c][n] -> fp16 same layout.
// ---------------------------------------------------------------------------
__global__ __launch_bounds__(256) void cvt_v_f16(
    const float* __restrict__ in, unsigned short* __restrict__ out)
{
    const size_t i = (size_t)blockIdx.x * 256 + threadIdx.x;   // per float4
    float4 v = ((const float4*)in)[i];
    unsigned lo = (unsigned)f2h(v.x) | ((unsigned)f2h(v.y) << 16);
    unsigned hi = (unsigned)f2h(v.z) | ((unsigned)f2h(v.w) << 16);
    ((uint2*)out)[i] = make_uint2(lo, hi);
}

// ---------------------------------------------------------------------------
// Flash attention, fp16 MFMA 16x16x32, S^T = K.Q^T.
// LDS ping-pong double buffer, ONE barrier per 64-key tile:
//   barrier -> issue 6 transient uint4 global loads (tile k+1)
//           -> compute tile k -> 6 ds_writes (tile k+1).
// No register state crosses a barrier => no scratch spills (R4 bug).
// XOR chunk-swizzle (chunk ^= row&7) on staging writes and frag reads.
// Block: 4 waves x 16 rows = 64 rows; 512 blocks (b = blk&7). LDS 56 KB.
// ---------------------------------------------------------------------------
__global__ __launch_bounds__(256, 2) void flash4_kernel(
    const unsigned short* __restrict__ Qw,   // [8][4096][64] fp16
    const unsigned short* __restrict__ Kw,   // [8][4096][64] fp16
    const unsigned short* __restrict__ Vw,   // [8][128][4096] fp16
    const float* __restrict__ Gw,            // [8][128][4096] fp32 gate
    float* __restrict__ out)                 // [8][128][4096]
{
    __shared__ __align__(16) unsigned short Ks[2][64 * 64];
    __shared__ __align__(16) unsigned short Vs[2][128 * 64];
    __shared__ __align__(16) unsigned short Ps[64 * 64];

    const int t = threadIdx.x;
    const int b = blockIdx.x & 7;
    const int n0 = (blockIdx.x >> 3) << 6;
    const int w = t >> 6, lane = t & 63;
    const int lg = (lane >> 4) & 3, lm = lane & 15;
    const int row_q = w * 16 + lm;
    const int swz = lm & 7;

    const unsigned short* Qb = Qw + ((size_t)b * kN) * kCH;
    const unsigned short* Kb = Kw + ((size_t)b * kN) * kCH;
    const unsigned short* Vb = Vw + ((size_t)b * kC) * kN;

    // Q fragments: registers for the whole kernel
    f16x8 qf0 = *(const f16x8*)(Qb + (size_t)(n0 + row_q) * kCH + (lg << 3));
    f16x8 qf1 = *(const f16x8*)(Qb + (size_t)(n0 + row_q) * kCH + 32 + (lg << 3));

    // staging geometry: thread covers chunk sc of rows sr, sr+32 (K) and
    // sr+{0,32,64,96} (V); stored chunk is XOR-swizzled by row&7
    const int sr  = t >> 3;                  // 0..31
    const int sc  = t & 7;
    const int scs = (sc ^ (sr & 7)) << 3;    // stored chunk offset (shorts)
    const int sg  = sc << 3;                 // global chunk offset

    // fragment-read offsets
    const int fswz0 = (lg ^ swz) << 3;
    const int fswz1 = ((4 | lg) ^ swz) << 3;
    int psw[4];
    #pragma unroll
    for (int mb = 0; mb < 4; ++mb)
        psw[mb] = row_q * 64 + (((2 * mb + (lg >> 1)) ^ swz) << 3) + ((lg & 1) << 2);

    f32x4 O[8];
    #pragma unroll
    for (int cb = 0; cb < 8; ++cb) O[cb] = (f32x4){0.f, 0.f, 0.f, 0.f};
    float m_run = 0.0f, l_run = 0.0f;        // S >= 0 (relu inputs)

    // ---- prologue: stage tile 0 into buffer 0 ----
    {
        uint4 k0 = *(const uint4*)(Kb + (size_t)(sr)      * kCH + sg);
        uint4 k1 = *(const uint4*)(Kb + (size_t)(sr + 32) * kCH + sg);
        uint4 v0 = *(const uint4*)(Vb + (size_t)(sr)      * kN + sg);
        uint4 v1 = *(const uint4*)(Vb + (size_t)(sr + 32) * kN + sg);
        uint4 v2 = *(const uint4*)(Vb + (size_t)(sr + 64) * kN + sg);
        uint4 v3 = *(const uint4*)(Vb + (size_t)(sr + 96) * kN + sg);
        *(uint4*)(Ks[0] + sr * 64 + scs)        = k0;
        *(uint4*)(Ks[0] + (sr + 32) * 64 + scs) = k1;
        *(uint4*)(Vs[0] + sr * 64 + scs)        = v0;
        *(uint4*)(Vs[0] + (sr + 32) * 64 + scs) = v1;
        *(uint4*)(Vs[0] + (sr + 64) * 64 + scs) = v2;
        *(uint4*)(Vs[0] + (sr + 96) * 64 + scs) = v3;
    }

    for (int kt = 0; kt < kN / 64; ++kt) {
        const int cur = kt & 1;
        __syncthreads();                     // cur staged; cur^1 free

        // ---- issue next tile's global loads (transient regs) ----
        uint4 k0, k1, v0, v1, v2, v3;
        const bool pre = (kt < kN / 64 - 1);
        if (pre) {
            const int m0 = (kt + 1) << 6;
            k0 = *(const uint4*)(Kb + (size_t)(m0 + sr)      * kCH + sg);
            k1 = *(const uint4*)(Kb + (size_t)(m0 + sr + 32) * kCH + sg);
            v0 = *(const uint4*)(Vb + (size_t)(sr)      * kN + m0 + sg);
            v1 = *(const uint4*)(Vb + (size_t)(sr + 32) * kN + m0 + sg);
            v2 = *(const uint4*)(Vb + (size_t)(sr + 64) * kN + m0 + sg);
            v3 = *(const uint4*)(Vb + (size_t)(sr + 96) * kN + m0 + sg);
        }

        // ---- QK^T -> S^T ----
        f32x4 s[4];
        #pragma unroll
        for (int mb = 0; mb < 4; ++mb) {
            const unsigned short* kr = Ks[cur] + ((mb * 16 + lm) << 6);
            f16x8 kf0 = *(const f16x8*)(kr + fswz0);
            f16x8 kf1 = *(const f16x8*)(kr + fswz1);
            f32x4 acc = (f32x4){0.f, 0.f, 0.f, 0.f};
            acc = __builtin_amdgcn_mfma_f32_16x16x32_f16(kf0, qf0, acc, 0, 0, 0);
            acc = __builtin_amdgcn_mfma_f32_16x16x32_f16(kf1, qf1, acc, 0, 0, 0);
            s[mb] = acc;
        }

        // ---- online softmax (row = lm; lane holds keys mb*16 + lg*4 + r) ----
        float mloc = 0.0f;
        #pragma unroll
        for (int mb = 0; mb < 4; ++mb)
            #pragma unroll
            for (int r = 0; r < 4; ++r) mloc = fmaxf(mloc, s[mb][r]);
        mloc = fmaxf(mloc, __shfl_xor(mloc, 16, 64));
        mloc = fmaxf(mloc, __shfl_xor(mloc, 32, 64));
        float mnew = fmaxf(m_run, mloc);
        float alpha = __expf(m_run - mnew);

        float psum = 0.0f;
        #pragma unroll
        for (int mb = 0; mb < 4; ++mb) {
            unsigned short h0 = f2h(__expf(s[mb][0] - mnew));
            unsigned short h1 = f2h(__expf(s[mb][1] - mnew));
            unsigned short h2 = f2h(__expf(s[mb][2] - mnew));
            unsigned short h3 = f2h(__expf(s[mb][3] - mnew));
            psum += (h2f(h0) + h2f(h1)) + (h2f(h2) + h2f(h3));   // rounded p's
            *(uint2*)(Ps + psw[mb]) = make_uint2((unsigned)h0 | ((unsigned)h1 << 16),
                                                 (unsigned)h2 | ((unsigned)h3 << 16));
        }
        psum += __shfl_xor(psum, 16, 64);
        psum += __shfl_xor(psum, 32, 64);
        l_run = l_run * alpha + psum;
        m_run = mnew;

        // rescale O (O-frag rows = tokens lg*4+r; alpha at lane==row)
        float a0 = __shfl(alpha, (lg << 2) + 0, 64);
        float a1 = __shfl(alpha, (lg << 2) + 1, 64);
        float a2 = __shfl(alpha, (lg << 2) + 2, 64);
        float a3 = __shfl(alpha, (lg << 2) + 3, 64);
        #pragma unroll
        for (int cb = 0; cb < 8; ++cb) {
            O[cb][0] *= a0; O[cb][1] *= a1; O[cb][2] *= a2; O[cb][3] *= a3;
        }

        // ---- PV ----
        f16x8 pf0 = *(const f16x8*)(Ps + row_q * 64 + fswz0);
        f16x8 pf1 = *(const f16x8*)(Ps + row_q * 64 + fswz1);
        #pragma unroll
        for (int cb = 0; cb < 8; ++cb) {
            const unsigned short* vr = Vs[cur] + ((cb * 16 + lm) << 6);
            f16x8 vf0 = *(const f16x8*)(vr + fswz0);
            f16x8 vf1 = *(const f16x8*)(vr + fswz1);
            O[cb] = __builtin_amdgcn_mfma_f32_16x16x32_f16(pf0, vf0, O[cb], 0, 0, 0);
            O[cb] = __builtin_amdgcn_mfma_f32_16x16x32_f16(pf1, vf1, O[cb], 0, 0, 0);
        }

        // ---- commit next tile into the other buffer ----
        if (pre) {
            unsigned short* Kn = Ks[cur ^ 1];
            unsigned short* Vn = Vs[cur ^ 1];
            *(uint4*)(Kn + sr * 64 + scs)        = k0;
            *(uint4*)(Kn + (sr + 32) * 64 + scs) = k1;
            *(uint4*)(Vn + sr * 64 + scs)        = v0;
            *(uint4*)(Vn + (sr + 32) * 64 + scs) = v1;
            *(uint4*)(Vn + (sr + 64) * 64 + scs) = v2;
            *(uint4*)(Vn + (sr + 96) * 64 + scs) = v3;
        }
    }

    // ---- epilogue: normalize, gate, store float4 (reg-quad = 4 tokens) ----
    float inv = 1.0f / l_run;
    float i0 = __shfl(inv, (lg << 2) + 0, 64);
    float i1 = __shfl(inv, (lg << 2) + 1, 64);
    float i2 = __shfl(inv, (lg << 2) + 2, 64);
    float i3 = __shfl(inv, (lg << 2) + 3, 64);
    const float* Gb = Gw + ((size_t)b * kC) * kN;
    float* Ob = out + ((size_t)b * kC) * kN;
    #pragma unroll
    for (int cb = 0; cb < 8; ++cb) {
        int c = cb * 16 + lm;
        size_t base = (size_t)c * kN + n0 + w * 16 + (lg << 2);
        float4 g = *(const float4*)(Gb + base);
        float4 res;
        res.x = O[cb][0] * i0 * g.x;
        res.y = O[cb][1] * i1 * g.y;
        res.z = O[cb][2] * i2 * g.z;
        res.w = O[cb][3] * i3 * g.w;
        *(float4*)(Ob + base) = res;
    }
}

// ---------------------------------------------------------------------------
extern "C" void kernel_launch(void* const* d_in, const int* in_sizes, int n_in,
                              void* d_out, int out_size, void* d_ws, size_t ws_size,
                              hipStream_t stream) {
    const float* tgt   = (const float*)d_in[0];
    const float* ref   = (const float*)d_in[1];
    const float* W_tgt = (const float*)d_in[2];
    const float* b_tgt = (const float*)d_in[3];
    const float* W_ref = (const float*)d_in[4];
    const float* b_ref = (const float*)d_in[5];
    const float* W_out = (const float*)d_in[6];
    const float* b_out = (const float*)d_in[7];
    float* out = (float*)d_out;

    const size_t QK = (size_t)8 * kN * kCH;              // 2M elems (fp16 -> 4 MB)
    const size_t CV = (size_t)8 * kC * kN;               // 4M elems (fp16 -> 8 MB)
    unsigned short* Qw = (unsigned short*)d_ws;          // 4 MB
    unsigned short* Kw = Qw + QK;                        // 4 MB
    unsigned short* Vw = Kw + QK;                        // 8 MB
    float*          Gw = (float*)(Vw + CV);              // 16 MB (total 32 MB)

    proj_qk2 <<<dim3(16, 2, 16), 256, 0, stream>>>(tgt, ref, W_tgt, W_ref,
                                                   b_tgt, b_ref, Qw, Kw);
    proj_gate2<<<dim3(16, 4, 8), 256, 0, stream>>>(tgt, W_out, b_out, Gw);
    cvt_v_f16 <<<dim3((8 * kC * kN) / 4 / 256), 256, 0, stream>>>(ref, Vw);

    flash4_kernel<<<dim3(512), 256, 0, stream>>>(Qw, Kw, Vw, Gw, out);
}

// Round 7
// 220.030 us; speedup vs baseline: 6.9636x; 1.0999x over previous
//
#include <hip/hip_runtime.h>

typedef __attribute__((ext_vector_type(8))) _Float16 f16x8;   // 8 fp16 = 4 VGPRs
typedef __attribute__((ext_vector_type(4))) float f32x4;

constexpr int kC  = 128;
constexpr int kCH = 64;
constexpr int kN  = 4096;
constexpr float kLog2e = 1.4426950408889634f;

__device__ __forceinline__ unsigned short f2h(float f) {
    union { _Float16 h; unsigned short u; } cv;
    cv.h = (_Float16)f;
    return cv.u;
}
__device__ __forceinline__ float h2f(unsigned short u) {
    union { _Float16 h; unsigned short u; } cv;
    cv.u = u;
    return (float)cv.h;
}
__device__ __forceinline__ unsigned pkrtz(float a, float b) {
    union { __fp16 __attribute__((ext_vector_type(2))) v; unsigned u; } cv;
    cv.v = __builtin_amdgcn_cvt_pkrtz(a, b);
    return cv.u;
}

// ---------------------------------------------------------------------------
// Unified projection kernel. Slices (blockIdx.y>>3):
//   0: Q = relu(Wt.tgt + bt) * log2e  -> fp16 [b][n][64]   (log2e folded => flash uses exp2)
//   1: K = relu(Wr.ref + br)          -> fp16 [b][n][64]
//   2: G[0:64]   = Wo.tgt + bo        -> fp32 [b][128][n]
//   3: G[64:128]
// Thread = 8 tok x 8 oc (64 FMA per 2 LDS-b128 + 2 X-float4). W^T in LDS
// (stride 65, conflict-free). Block 256 thr = 256 tok x 64 oc. Grid (16, 32).
// ---------------------------------------------------------------------------
__global__ __launch_bounds__(256, 3) void proj_all(
    const float* __restrict__ tgt, const float* __restrict__ ref,
    const float* __restrict__ Wt, const float* __restrict__ Wr,
    const float* __restrict__ Wo, const float* __restrict__ bt,
    const float* __restrict__ br, const float* __restrict__ bo,
    unsigned short* __restrict__ Qw, unsigned short* __restrict__ Kw,
    float* __restrict__ Gw)
{
    __shared__ float ws[128 * 65];           // ws[c][oc], 64 oc per slice
    const int t = threadIdx.x;
    const int slice = blockIdx.y >> 3;
    const int b = blockIdx.y & 7;
    const int tokb = blockIdx.x * 256;

    const float* X;
    const float* W;
    const float* bias;
    int oc0 = 0;
    float scale = 1.0f;
    if (slice == 0)      { X = tgt; W = Wt; bias = bt; scale = kLog2e; }
    else if (slice == 1) { X = ref; W = Wr; bias = br; }
    else                 { X = tgt; W = Wo; bias = bo; oc0 = (slice - 2) * 64; }

    #pragma unroll
    for (int k = 0; k < 32; ++k) {
        int i = t + k * 256;                 // 0..8191
        int c = i & 127, oc = i >> 7;        // consecutive t -> consecutive c (coalesced)
        ws[c * 65 + oc] = W[(size_t)(oc0 + oc) * kC + c] * scale;
    }
    __syncthreads();

    const int tokg = t >> 3;                 // 0..31
    const int ocg  = t & 7;                  // 0..7
    const int tok0 = tokb + tokg * 8;

    float bv[8];
    #pragma unroll
    for (int j = 0; j < 8; ++j) bv[j] = bias[oc0 + ocg * 8 + j] * scale;
    float acc[8][8];
    #pragma unroll
    for (int i = 0; i < 8; ++i)
        #pragma unroll
        for (int j = 0; j < 8; ++j) acc[i][j] = bv[j];

    const float* Xb = X + ((size_t)b * kC) * kN + tok0;
    #pragma unroll 2
    for (int c = 0; c < kC; ++c) {
        float4 x0 = *(const float4*)(Xb + (size_t)c * kN);
        float4 x1 = *(const float4*)(Xb + (size_t)c * kN + 4);
        float4 w0 = *(const float4*)(ws + c * 65 + ocg * 8);
        float4 w1 = *(const float4*)(ws + c * 65 + ocg * 8 + 4);
        float xx[8] = {x0.x, x0.y, x0.z, x0.w, x1.x, x1.y, x1.z, x1.w};
        float ww[8] = {w0.x, w0.y, w0.z, w0.w, w1.x, w1.y, w1.z, w1.w};
        #pragma unroll
        for (int i = 0; i < 8; ++i)
            #pragma unroll
            for (int j = 0; j < 8; ++j) acc[i][j] = fmaf(xx[i], ww[j], acc[i][j]);
    }

    if (slice < 2) {
        unsigned short* out = slice ? Kw : Qw;
        #pragma unroll
        for (int i = 0; i < 8; ++i) {
            uint4 pk;
            pk.x = pkrtz(fmaxf(acc[i][0], 0.f), fmaxf(acc[i][1], 0.f));
            pk.y = pkrtz(fmaxf(acc[i][2], 0.f), fmaxf(acc[i][3], 0.f));
            pk.z = pkrtz(fmaxf(acc[i][4], 0.f), fmaxf(acc[i][5], 0.f));
            pk.w = pkrtz(fmaxf(acc[i][6], 0.f), fmaxf(acc[i][7], 0.f));
            *(uint4*)(out + ((size_t)b * kN + tok0 + i) * kCH + ocg * 8) = pk;
        }
    } else {
        #pragma unroll
        for (int j = 0; j < 8; ++j) {
            size_t base = ((size_t)b * kC + oc0 + ocg * 8 + j) * kN + tok0;
            *(float4*)(Gw + base)     = make_float4(acc[0][j], acc[1][j], acc[2][j], acc[3][j]);
            *(float4*)(Gw + base + 4) = make_float4(acc[4][j], acc[5][j], acc[6][j], acc[7][j]);
        }
    }
}

// ---------------------------------------------------------------------------
// V convert: ref fp32 [b][c][n] -> fp16 same layout.
// ---------------------------------------------------------------------------
__global__ __launch_bounds__(256) void cvt_v_f16(
    const float* __restrict__ in, unsigned short* __restrict__ out)
{
    const size_t i = (size_t)blockIdx.x * 256 + threadIdx.x;   // per float4
    float4 v = ((const float4*)in)[i];
    ((uint2*)out)[i] = make_uint2(pkrtz(v.x, v.y), pkrtz(v.z, v.w));
}

// ---------------------------------------------------------------------------
// Flash attention, fp16 MFMA 16x16x32, S^T = K.Q^T. R5-validated structure:
// LDS ping-pong double buffer, one barrier per 64-key tile.
// R6 deltas: Q pre-scaled by log2e -> exp2f (bare v_exp_f32); P packed via
// v_cvt_pkrtz; O-rescale skipped under wave-uniform __any(max-updated) guard.
// ---------------------------------------------------------------------------
__global__ __launch_bounds__(256, 2) void flash5_kernel(
    const unsigned short* __restrict__ Qw,   // [8][4096][64] fp16 (x log2e)
    const unsigned short* __restrict__ Kw,   // [8][4096][64] fp16
    const unsigned short* __restrict__ Vw,   // [8][128][4096] fp16
    const float* __restrict__ Gw,            // [8][128][4096] fp32 gate
    float* __restrict__ out)                 // [8][128][4096]
{
    __shared__ __align__(16) unsigned short Ks[2][64 * 64];
    __shared__ __align__(16) unsigned short Vs[2][128 * 64];
    __shared__ __align__(16) unsigned short Ps[64 * 64];

    const int t = threadIdx.x;
    const int b = blockIdx.x & 7;
    const int n0 = (blockIdx.x >> 3) << 6;
    const int w = t >> 6, lane = t & 63;
    const int lg = (lane >> 4) & 3, lm = lane & 15;
    const int row_q = w * 16 + lm;
    const int swz = lm & 7;

    const unsigned short* Qb = Qw + ((size_t)b * kN) * kCH;
    const unsigned short* Kb = Kw + ((size_t)b * kN) * kCH;
    const unsigned short* Vb = Vw + ((size_t)b * kC) * kN;

    f16x8 qf0 = *(const f16x8*)(Qb + (size_t)(n0 + row_q) * kCH + (lg << 3));
    f16x8 qf1 = *(const f16x8*)(Qb + (size_t)(n0 + row_q) * kCH + 32 + (lg << 3));

    const int sr  = t >> 3;                  // 0..31
    const int sc  = t & 7;
    const int scs = (sc ^ (sr & 7)) << 3;
    const int sg  = sc << 3;

    const int fswz0 = (lg ^ swz) << 3;
    const int fswz1 = ((4 | lg) ^ swz) << 3;
    int psw[4];
    #pragma unroll
    for (int mb = 0; mb < 4; ++mb)
        psw[mb] = row_q * 64 + (((2 * mb + (lg >> 1)) ^ swz) << 3) + ((lg & 1) << 2);

    f32x4 O[8];
    #pragma unroll
    for (int cb = 0; cb < 8; ++cb) O[cb] = (f32x4){0.f, 0.f, 0.f, 0.f};
    float m_run = 0.0f, l_run = 0.0f;        // S >= 0 (relu inputs), exp2 domain

    {   // prologue: stage tile 0 into buffer 0
        uint4 k0 = *(const uint4*)(Kb + (size_t)(sr)      * kCH + sg);
        uint4 k1 = *(const uint4*)(Kb + (size_t)(sr + 32) * kCH + sg);
        uint4 v0 = *(const uint4*)(Vb + (size_t)(sr)      * kN + sg);
        uint4 v1 = *(const uint4*)(Vb + (size_t)(sr + 32) * kN + sg);
        uint4 v2 = *(const uint4*)(Vb + (size_t)(sr + 64) * kN + sg);
        uint4 v3 = *(const uint4*)(Vb + (size_t)(sr + 96) * kN + sg);
        *(uint4*)(Ks[0] + sr * 64 + scs)        = k0;
        *(uint4*)(Ks[0] + (sr + 32) * 64 + scs) = k1;
        *(uint4*)(Vs[0] + sr * 64 + scs)        = v0;
        *(uint4*)(Vs[0] + (sr + 32) * 64 + scs) = v1;
        *(uint4*)(Vs[0] + (sr + 64) * 64 + scs) = v2;
        *(uint4*)(Vs[0] + (sr + 96) * 64 + scs) = v3;
    }

    for (int kt = 0; kt < kN / 64; ++kt) {
        const int cur = kt & 1;
        __syncthreads();

        uint4 k0, k1, v0, v1, v2, v3;
        const bool pre = (kt < kN / 64 - 1);
        if (pre) {
            const int m0 = (kt + 1) << 6;
            k0 = *(const uint4*)(Kb + (size_t)(m0 + sr)      * kCH + sg);
            k1 = *(const uint4*)(Kb + (size_t)(m0 + sr + 32) * kCH + sg);
            v0 = *(const uint4*)(Vb + (size_t)(sr)      * kN + m0 + sg);
            v1 = *(const uint4*)(Vb + (size_t)(sr + 32) * kN + m0 + sg);
            v2 = *(const uint4*)(Vb + (size_t)(sr + 64) * kN + m0 + sg);
            v3 = *(const uint4*)(Vb + (size_t)(sr + 96) * kN + m0 + sg);
        }

        // ---- QK^T -> S^T (log2 domain) ----
        f32x4 s[4];
        #pragma unroll
        for (int mb = 0; mb < 4; ++mb) {
            const unsigned short* kr = Ks[cur] + ((mb * 16 + lm) << 6);
            f16x8 kf0 = *(const f16x8*)(kr + fswz0);
            f16x8 kf1 = *(const f16x8*)(kr + fswz1);
            f32x4 acc = (f32x4){0.f, 0.f, 0.f, 0.f};
            acc = __builtin_amdgcn_mfma_f32_16x16x32_f16(kf0, qf0, acc, 0, 0, 0);
            acc = __builtin_amdgcn_mfma_f32_16x16x32_f16(kf1, qf1, acc, 0, 0, 0);
            s[mb] = acc;
        }

        // ---- online softmax (base 2) ----
        float mloc = 0.0f;
        #pragma unroll
        for (int mb = 0; mb < 4; ++mb)
            #pragma unroll
            for (int r = 0; r < 4; ++r) mloc = fmaxf(mloc, s[mb][r]);
        mloc = fmaxf(mloc, __shfl_xor(mloc, 16, 64));
        mloc = fmaxf(mloc, __shfl_xor(mloc, 32, 64));
        const bool upd = __any(mloc > m_run);
        float mnew = upd ? fmaxf(m_run, mloc) : m_run;

        float psum = 0.0f;
        #pragma unroll
        for (int mb = 0; mb < 4; ++mb) {
            unsigned plo = pkrtz(exp2f(s[mb][0] - mnew), exp2f(s[mb][1] - mnew));
            unsigned phi = pkrtz(exp2f(s[mb][2] - mnew), exp2f(s[mb][3] - mnew));
            // denominator from the ROUNDED p's (matches PV numerator)
            psum += (h2f(plo & 0xffff) + h2f(plo >> 16)) +
                    (h2f(phi & 0xffff) + h2f(phi >> 16));
            *(uint2*)(Ps + psw[mb]) = make_uint2(plo, phi);
        }
        psum += __shfl_xor(psum, 16, 64);
        psum += __shfl_xor(psum, 32, 64);

        if (upd) {
            float alpha = exp2f(m_run - mnew);
            float a0 = __shfl(alpha, (lg << 2) + 0, 64);
            float a1 = __shfl(alpha, (lg << 2) + 1, 64);
            float a2 = __shfl(alpha, (lg << 2) + 2, 64);
            float a3 = __shfl(alpha, (lg << 2) + 3, 64);
            #pragma unroll
            for (int cb = 0; cb < 8; ++cb) {
                O[cb][0] *= a0; O[cb][1] *= a1; O[cb][2] *= a2; O[cb][3] *= a3;
            }
            l_run = l_run * alpha + psum;
            m_run = mnew;
        } else {
            l_run += psum;
        }

        // ---- PV ----
        f16x8 pf0 = *(const f16x8*)(Ps + row_q * 64 + fswz0);
        f16x8 pf1 = *(const f16x8*)(Ps + row_q * 64 + fswz1);
        #pragma unroll
        for (int cb = 0; cb < 8; ++cb) {
            const unsigned short* vr = Vs[cur] + ((cb * 16 + lm) << 6);
            f16x8 vf0 = *(const f16x8*)(vr + fswz0);
            f16x8 vf1 = *(const f16x8*)(vr + fswz1);
            O[cb] = __builtin_amdgcn_mfma_f32_16x16x32_f16(pf0, vf0, O[cb], 0, 0, 0);
            O[cb] = __builtin_amdgcn_mfma_f32_16x16x32_f16(pf1, vf1, O[cb], 0, 0, 0);
        }

        if (pre) {
            unsigned short* Kn = Ks[cur ^ 1];
            unsigned short* Vn = Vs[cur ^ 1];
            *(uint4*)(Kn + sr * 64 + scs)        = k0;
            *(uint4*)(Kn + (sr + 32) * 64 + scs) = k1;
            *(uint4*)(Vn + sr * 64 + scs)        = v0;
            *(uint4*)(Vn + (sr + 32) * 64 + scs) = v1;
            *(uint4*)(Vn + (sr + 64) * 64 + scs) = v2;
            *(uint4*)(Vn + (sr + 96) * 64 + scs) = v3;
        }
    }

    // ---- epilogue: normalize, gate, store float4 (reg-quad = 4 tokens) ----
    float inv = 1.0f / l_run;
    float i0 = __shfl(inv, (lg << 2) + 0, 64);
    float i1 = __shfl(inv, (lg << 2) + 1, 64);
    float i2 = __shfl(inv, (lg << 2) + 2, 64);
    float i3 = __shfl(inv, (lg << 2) + 3, 64);
    const float* Gb = Gw + ((size_t)b * kC) * kN;
    float* Ob = out + ((size_t)b * kC) * kN;
    #pragma unroll
    for (int cb = 0; cb < 8; ++cb) {
        int c = cb * 16 + lm;
        size_t base = (size_t)c * kN + n0 + w * 16 + (lg << 2);
        float4 g = *(const float4*)(Gb + base);
        float4 res;
        res.x = O[cb][0] * i0 * g.x;
        res.y = O[cb][1] * i1 * g.y;
        res.z = O[cb][2] * i2 * g.z;
        res.w = O[cb][3] * i3 * g.w;
        *(float4*)(Ob + base) = res;
    }
}

// ---------------------------------------------------------------------------
extern "C" void kernel_launch(void* const* d_in, const int* in_sizes, int n_in,
                              void* d_out, int out_size, void* d_ws, size_t ws_size,
                              hipStream_t stream) {
    const float* tgt   = (const float*)d_in[0];
    const float* ref   = (const float*)d_in[1];
    const float* W_tgt = (const float*)d_in[2];
    const float* b_tgt = (const float*)d_in[3];
    const float* W_ref = (const float*)d_in[4];
    const float* b_ref = (const float*)d_in[5];
    const float* W_out = (const float*)d_in[6];
    const float* b_out = (const float*)d_in[7];
    float* out = (float*)d_out;

    const size_t QK = (size_t)8 * kN * kCH;              // fp16 -> 4 MB each
    const size_t CV = (size_t)8 * kC * kN;               // fp16 -> 8 MB
    unsigned short* Qw = (unsigned short*)d_ws;          // 4 MB
    unsigned short* Kw = Qw + QK;                        // 4 MB
    unsigned short* Vw = Kw + QK;                        // 8 MB
    float*          Gw = (float*)(Vw + CV);              // 16 MB (total 32 MB)

    proj_all <<<dim3(16, 32), 256, 0, stream>>>(tgt, ref, W_tgt, W_ref, W_out,
                                                b_tgt, b_ref, b_out, Qw, Kw, Gw);
    cvt_v_f16<<<dim3((8 * kC * kN) / 4 / 256), 256, 0, stream>>>(ref, Vw);

    flash5_kernel<<<dim3(512), 256, 0, stream>>>(Qw, Kw, Vw, Gw, out);
}